// Round 5
// baseline (1991.836 us; speedup 1.0000x reference)
//
#include <hip/hip_runtime.h>

#define BB 64
#define TT 4995
#define VV 4096
#define EE 100
#define UU 64
#define U3 192
#define BPB 4             // batch rows per block (spread across D lane-groups)
#define NBLK (BB / BPB)   // 16 blocks

using bf16x8 = __attribute__((ext_vector_type(8))) short;
using f32x4  = __attribute__((ext_vector_type(4))) float;

#define MFMA16 __builtin_amdgcn_mfma_f32_16x16x32_bf16

// Lightweight barrier: LDS-visibility only (lgkmcnt), does NOT drain vmcnt,
// so the global xp/token prefetch stays in flight across steps.
#define LDS_BARRIER() asm volatile("s_waitcnt lgkmcnt(0)\ns_barrier" ::: "memory")

// Static device workspace: embW[v][k] = (emb @ W1 + b1[0])[v][k], 3.07 MB (L2-resident).
__device__ float g_embW[VV * U3];

__device__ __forceinline__ float fast_sigmoid(float x) {
    return __builtin_amdgcn_rcpf(1.0f + __expf(-x));
}
__device__ __forceinline__ float fast_tanh(float x) {
    return __builtin_amdgcn_rcpf(1.0f + __expf(-2.0f * x)) * 2.0f - 1.0f;
}
// f32 -> bf16 round-to-nearest-even
__device__ __forceinline__ unsigned short f2bf(float f) {
    unsigned u = __float_as_uint(f);
    return (unsigned short)((u + 0x7FFFu + ((u >> 16) & 1u)) >> 16);
}
__device__ __forceinline__ float bf2f(unsigned short h) {
    return __uint_as_float(((unsigned)h) << 16);
}

// Kernel A: embW[v][k] = sum_j emb[v][j] * W1[j][k] + b1[0][k]  (fp32 table)
__global__ void gru_embw_kernel(const float* __restrict__ emb,
                                const float* __restrict__ W1,
                                const float* __restrict__ b1) {
    __shared__ float row[EE];
    const int v = blockIdx.x;
    const int k = threadIdx.x;  // 0..191
    if (k < EE) row[k] = emb[v * EE + k];
    __syncthreads();
    float acc = b1[k];
    #pragma unroll 4
    for (int j = 0; j < EE; ++j)
        acc = fmaf(row[j], W1[j * U3 + k], acc);
    g_embW[v * U3 + k] = acc;
}

// Kernel B: MFMA-based fused 2-layer GRU scan, 16 blocks x 4 batch rows.
// Batch row rb (0..3) lives at MFMA/LDS row 4*rb -> every lane owns exactly
// one (row,unit) gate at reg 0. Waves 0-3 = layer1, waves 4-7 = layer2,
// each owning a 16-unit column tile. Weights persist as B-fragments.
// R5 changes vs R4: (1) all MFMAs per gate are INDEPENDENT (C = invariant
// bias/zero quads), reg[0] partial sums added on VALU -> dependent-MFMA
// chain removed from critical path; (2) no per-step accumulator-init movs;
// (3) lgkmcnt-only barrier keeps global prefetch in flight; (4) L1 waves
// no longer read the unused h2 fragments.
__global__ __launch_bounds__(512, 1)
void gru_scan_kernel(const int* __restrict__ tokens,
                     const float* __restrict__ U1,
                     const float* __restrict__ b1,
                     const float* __restrict__ W2,
                     const float* __restrict__ U2,
                     const float* __restrict__ b2,
                     const float* __restrict__ Wout,
                     const float* __restrict__ bout,
                     float* __restrict__ out) {
    const int blk  = blockIdx.x;
    const int tid  = threadIdx.x;
    const int wave = tid >> 6;
    const int lane = tid & 63;
    const int lg   = lane >> 4;   // 0..3: k-chunk group (A/B), row group (D)
    const int lc   = lane & 15;   // 0..15: A-row / D-col
    const bool isL2 = (wave >= 4);
    const int ut   = wave & 3;    // unit tile (16 units) this wave owns

    // h state: [buf(2)][which(2: h1,h2)][row 16][unit 64] bf16, XOR-swizzled:
    // byte = ((buf*2+which)*16 + row)*128 + ((unit*2) ^ ((row&7)<<4))
    // Rows != 0,4,8,12 are never written -> stay zero (harmless in MFMA).
    __shared__ __align__(16) char hls[8192];
    for (int i = tid; i < 2048; i += 512) ((int*)hls)[i] = 0;

    // ---- weight B-fragments (once). k-map: k = 8*lg + 32*kk + e.
    // A uses the same k-map, so any HW k-permutation cancels (A/B mirrored).
    bf16x8 fb[12];
    const int cz = ut * 16 + lc;          // z gate column
    const int cr = 64 + ut * 16 + lc;     // r gate column
    const int ch = 128 + ut * 16 + lc;    // hh gate column
    {
        const float* M0 = isL2 ? W2 : U1;
        #pragma unroll
        for (int g = 0; g < 3; ++g) {
            const int col = g * 64 + ut * 16 + lc;
            #pragma unroll
            for (int kk = 0; kk < 2; ++kk) {
                bf16x8 v;
                #pragma unroll
                for (int e = 0; e < 8; ++e)
                    v[e] = (short)f2bf(M0[(8 * lg + 32 * kk + e) * U3 + col]);
                fb[g * 2 + kk] = v;
            }
        }
        if (isL2) {
            #pragma unroll
            for (int g = 0; g < 3; ++g) {
                const int col = g * 64 + ut * 16 + lc;
                #pragma unroll
                for (int kk = 0; kk < 2; ++kk) {
                    bf16x8 v;
                    #pragma unroll
                    for (int e = 0; e < 8; ++e)
                        v[e] = (short)f2bf(U2[(8 * lg + 32 * kk + e) * U3 + col]);
                    fb[6 + g * 2 + kk] = v;
                }
            }
        } else {
            #pragma unroll
            for (int q = 6; q < 12; ++q) fb[q] = fb[q - 6];  // keep defined
        }
    }

    // biases as loop-invariant MFMA C-operand quads (no per-step init movs)
    float bias_z, bias_r, bias_h, bias_h2 = 0.0f;
    if (!isL2) {
        bias_z = b1[U3 + cz]; bias_r = b1[U3 + cr]; bias_h = b1[U3 + ch];
    } else {
        bias_z  = b2[cz] + b2[U3 + cz];
        bias_r  = b2[cr] + b2[U3 + cr];
        bias_h  = b2[ch];         // xh init (input-side bias)
        bias_h2 = b2[U3 + ch];    // hph init (recurrent bias)
    }
    const f32x4 bz4 = {bias_z, bias_z, bias_z, bias_z};
    const f32x4 br4 = {bias_r, bias_r, bias_r, bias_r};
    const f32x4 bh4 = {bias_h, bias_h, bias_h, bias_h};
    const f32x4 bp4 = {bias_h2, bias_h2, bias_h2, bias_h2};
    const f32x4 zq  = {0.0f, 0.0f, 0.0f, 0.0f};

    // ---- xp/token prefetch pipeline (L1 waves). Each lane serves its ONE
    // batch row (rb = lg): 3 embW floats + 1 token per step.
    float xp[2][3];
    int   tok[2];
    const int rowbase = (blk * BPB + lg) * TT;   // this lane's token row
    if (!isL2) {
        const int t0 = tokens[rowbase];
        tok[0] = tokens[rowbase + 1];
        tok[1] = tokens[rowbase + 2];
        xp[0][0] = g_embW[t0 * U3 + cz];
        xp[0][1] = g_embW[t0 * U3 + cr];
        xp[0][2] = g_embW[t0 * U3 + ch];
    }

    float h1o = 0.0f;   // h1(s-1) master copy (L1 waves)
    float h2o = 0.0f;   // h2(s-2) master copy (L2 waves)

    __syncthreads();    // full barrier once after LDS zero-init

    const int swzA = (lc & 7) << 4;              // A-read row swizzle (row = lc)
    const int myrow = 4 * lg;                    // this lane's MFMA/LDS row
    const int wswz  = ((myrow & 7) << 4);        // write swizzle for that row
    const int wbyte = myrow * 128 + (((ut * 16 + lc) * 2) ^ wswz);

    #pragma unroll 1
    for (int sb = 0; sb < TT + 1; sb += 2) {      // TT+1 = 4996 steps total
        #pragma unroll
        for (int half = 0; half < 2; ++half) {
            const int s = sb + half;              // step
            char* rdb = hls + half * 4096;        // read buffer
            char* wrb = hls + (half ^ 1) * 4096;  // write buffer

            if (!isL2) {
                // A-fragments (h1 only): rows=batch (lc), k=units.
                bf16x8 a1_0 = *(const bf16x8*)(rdb + lc * 128 + ((16 * lg) ^ swzA));
                bf16x8 a1_1 = *(const bf16x8*)(rdb + lc * 128 + ((16 * lg + 64) ^ swzA));

                // prefetch xp for step s+1 (tok[half] = tokens[s+1]) and
                // the token for s+2 into tok[half^1]
                const int tn = tok[half];
                xp[half ^ 1][0] = g_embW[tn * U3 + cz];
                xp[half ^ 1][1] = g_embW[tn * U3 + cr];
                xp[half ^ 1][2] = g_embW[tn * U3 + ch];
                const int s2 = (s + 2 < TT) ? (s + 2) : (TT - 1);
                tok[half ^ 1] = tokens[rowbase + s2];

                if (s < TT) {   // layer 1 computes h1(s)
                    // independent MFMAs; only reg[0] consumed
                    const f32x4 azA = MFMA16(a1_0, fb[0], bz4, 0, 0, 0);
                    const f32x4 azB = MFMA16(a1_1, fb[1], zq,  0, 0, 0);
                    const f32x4 arA = MFMA16(a1_0, fb[2], br4, 0, 0, 0);
                    const f32x4 arB = MFMA16(a1_1, fb[3], zq,  0, 0, 0);
                    const f32x4 ahA = MFMA16(a1_0, fb[4], bh4, 0, 0, 0);
                    const f32x4 ahB = MFMA16(a1_1, fb[5], zq,  0, 0, 0);
                    const float z  = fast_sigmoid(xp[half][0] + (azA[0] + azB[0]));
                    const float rg = fast_sigmoid(xp[half][1] + (arA[0] + arB[0]));
                    const float hh = fast_tanh(xp[half][2] + rg * (ahA[0] + ahB[0]));
                    h1o = z * h1o + (1.0f - z) * hh;
                    *(unsigned short*)(wrb + wbyte) = f2bf(h1o);
                }
            } else {
                // A-fragments: h1 (for W2) and h2 (for U2)
                bf16x8 a1_0 = *(const bf16x8*)(rdb + lc * 128 + ((16 * lg) ^ swzA));
                bf16x8 a1_1 = *(const bf16x8*)(rdb + lc * 128 + ((16 * lg + 64) ^ swzA));
                bf16x8 a2_0 = *(const bf16x8*)(rdb + 2048 + lc * 128 + ((16 * lg) ^ swzA));
                bf16x8 a2_1 = *(const bf16x8*)(rdb + 2048 + lc * 128 + ((16 * lg + 64) ^ swzA));

                if (s > 0) {    // layer 2 computes h2(s-1)
                    const f32x4 azA = MFMA16(a1_0, fb[0],  bz4, 0, 0, 0);  // h1@W2 (z)
                    const f32x4 azB = MFMA16(a1_1, fb[1],  zq,  0, 0, 0);
                    const f32x4 azC = MFMA16(a2_0, fb[6],  zq,  0, 0, 0);  // h2@U2 (z)
                    const f32x4 azD = MFMA16(a2_1, fb[7],  zq,  0, 0, 0);
                    const f32x4 arA = MFMA16(a1_0, fb[2],  br4, 0, 0, 0);
                    const f32x4 arB = MFMA16(a1_1, fb[3],  zq,  0, 0, 0);
                    const f32x4 arC = MFMA16(a2_0, fb[8],  zq,  0, 0, 0);
                    const f32x4 arD = MFMA16(a2_1, fb[9],  zq,  0, 0, 0);
                    const f32x4 axA = MFMA16(a1_0, fb[4],  bh4, 0, 0, 0);  // xh
                    const f32x4 axB = MFMA16(a1_1, fb[5],  zq,  0, 0, 0);
                    const f32x4 apA = MFMA16(a2_0, fb[10], bp4, 0, 0, 0);  // hph
                    const f32x4 apB = MFMA16(a2_1, fb[11], zq,  0, 0, 0);
                    const float zs = (azA[0] + azB[0]) + (azC[0] + azD[0]);
                    const float rs = (arA[0] + arB[0]) + (arC[0] + arD[0]);
                    const float z  = fast_sigmoid(zs);
                    const float rg = fast_sigmoid(rs);
                    const float hh = fast_tanh((axA[0] + axB[0]) + rg * (apA[0] + apB[0]));
                    h2o = z * h2o + (1.0f - z) * hh;
                    *(unsigned short*)(wrb + 2048 + wbyte) = f2bf(h2o);
                }
            }
            LDS_BARRIER();
        }
    }

    // ---- output head: h2(TT-1) sits in buf0/which=1 (step TT wrote buf0).
    // Lane j (0..3) of wave 0 handles batch row j at LDS row 4*j.
    if (wave == 0 && lane < BPB) {
        const int row = 4 * lane;
        float acc = bout[0];
        #pragma unroll 8
        for (int u = 0; u < UU; ++u) {
            const unsigned short hv = *(const unsigned short*)(hls + 2048 +
                row * 128 + ((u * 2) ^ ((row & 7) << 4)));
            acc = fmaf(bf2f(hv), Wout[u], acc);
        }
        out[blk * BPB + lane] = fast_sigmoid(acc);
    }
}

extern "C" void kernel_launch(void* const* d_in, const int* in_sizes, int n_in,
                              void* d_out, int out_size, void* d_ws, size_t ws_size,
                              hipStream_t stream) {
    const int*   tokens = (const int*)  d_in[0];
    const float* emb    = (const float*)d_in[1];
    const float* W1     = (const float*)d_in[2];
    const float* U1w    = (const float*)d_in[3];
    const float* b1     = (const float*)d_in[4];
    const float* W2     = (const float*)d_in[5];
    const float* U2w    = (const float*)d_in[6];
    const float* b2     = (const float*)d_in[7];
    const float* Wout   = (const float*)d_in[8];
    const float* bout   = (const float*)d_in[9];
    float* out = (float*)d_out;

    gru_embw_kernel<<<VV, 192, 0, stream>>>(emb, W1, b1);
    gru_scan_kernel<<<NBLK, 512, 0, stream>>>(tokens, U1w, b1, W2, U2w,
                                              b2, Wout, bout, out);
}

// Round 6
// 1649.441 us; speedup vs baseline: 1.2076x; 1.2076x over previous
//
#include <hip/hip_runtime.h>

#define BB 64
#define TT 4995
#define VV 4096
#define EE 100
#define UU 64
#define U3 192
#define BPB 4             // batch rows per block (spread across D lane-groups)
#define NBLK (BB / BPB)   // 16 blocks

using bf16x8 = __attribute__((ext_vector_type(8))) short;
using f32x4  = __attribute__((ext_vector_type(4))) float;

#define MFMA16 __builtin_amdgcn_mfma_f32_16x16x32_bf16

// Static device workspace: embW[v][k] = (emb @ W1 + b1[0])[v][k], 3.07 MB (L2-resident).
__device__ float g_embW[VV * U3];

__device__ __forceinline__ float fast_sigmoid(float x) {
    return __builtin_amdgcn_rcpf(1.0f + __expf(-x));
}
__device__ __forceinline__ float fast_tanh(float x) {
    return __builtin_amdgcn_rcpf(1.0f + __expf(-2.0f * x)) * 2.0f - 1.0f;
}
// f32 -> bf16 round-to-nearest-even
__device__ __forceinline__ unsigned short f2bf(float f) {
    unsigned u = __float_as_uint(f);
    return (unsigned short)((u + 0x7FFFu + ((u >> 16) & 1u)) >> 16);
}
__device__ __forceinline__ float bf2f(unsigned short h) {
    return __uint_as_float(((unsigned)h) << 16);
}

// Kernel A: embW[v][k] = sum_j emb[v][j] * W1[j][k] + b1[0][k]  (fp32 table)
__global__ void gru_embw_kernel(const float* __restrict__ emb,
                                const float* __restrict__ W1,
                                const float* __restrict__ b1) {
    __shared__ float row[EE];
    const int v = blockIdx.x;
    const int k = threadIdx.x;  // 0..191
    if (k < EE) row[k] = emb[v * EE + k];
    __syncthreads();
    float acc = b1[k];
    #pragma unroll 4
    for (int j = 0; j < EE; ++j)
        acc = fmaf(row[j], W1[j * U3 + k], acc);
    g_embW[v * U3 + k] = acc;
}

// Kernel B: MFMA-based fused 2-layer GRU scan, 16 blocks x 4 batch rows.
// Structure = verified R4 kernel (1609 us). R6 deltas (surgical, isolated):
//  - global xp/token prefetch issued at TOP of step (max latency hiding
//    before __syncthreads' vmcnt drain)
//  - L1 waves no longer read the unused h2 fragments
//  - bias quads fed directly as loop-invariant MFMA C operands (no per-step
//    accumulator-init movs); chains kept DEPENDENT (R5's full-independent
//    form regressed: too many live acc quads)
//  - L2 z/r gates: 4-dep MFMA chain -> two 2-dep chains + 1 VALU add
//  - h update as fmaf(z, h-hh, hh)
// Barrier remains __syncthreads() (R5's inline-asm barrier regressed).
__global__ __launch_bounds__(512, 1)
void gru_scan_kernel(const int* __restrict__ tokens,
                     const float* __restrict__ U1,
                     const float* __restrict__ b1,
                     const float* __restrict__ W2,
                     const float* __restrict__ U2,
                     const float* __restrict__ b2,
                     const float* __restrict__ Wout,
                     const float* __restrict__ bout,
                     float* __restrict__ out) {
    const int blk  = blockIdx.x;
    const int tid  = threadIdx.x;
    const int wave = tid >> 6;
    const int lane = tid & 63;
    const int lg   = lane >> 4;   // 0..3: k-chunk group (A/B), row group (D)
    const int lc   = lane & 15;   // 0..15: A-row / D-col
    const bool isL2 = (wave >= 4);
    const int ut   = wave & 3;    // unit tile (16 units) this wave owns

    // h state: [buf(2)][which(2: h1,h2)][row 16][unit 64] bf16, XOR-swizzled:
    // byte = ((buf*2+which)*16 + row)*128 + ((unit*2) ^ ((row&7)<<4))
    // Rows != 0,4,8,12 are never written -> stay zero (harmless in MFMA).
    __shared__ __align__(16) char hls[8192];
    for (int i = tid; i < 2048; i += 512) ((int*)hls)[i] = 0;

    // ---- weight B-fragments (once). k-map: k = 8*lg + 32*kk + e.
    // A uses the same k-map, so any HW k-permutation cancels (A/B mirrored).
    bf16x8 fb[12];
    const int cz = ut * 16 + lc;          // z gate column
    const int cr = 64 + ut * 16 + lc;     // r gate column
    const int ch = 128 + ut * 16 + lc;    // hh gate column
    {
        const float* M0 = isL2 ? W2 : U1;
        #pragma unroll
        for (int g = 0; g < 3; ++g) {
            const int col = g * 64 + ut * 16 + lc;
            #pragma unroll
            for (int kk = 0; kk < 2; ++kk) {
                bf16x8 v;
                #pragma unroll
                for (int e = 0; e < 8; ++e)
                    v[e] = (short)f2bf(M0[(8 * lg + 32 * kk + e) * U3 + col]);
                fb[g * 2 + kk] = v;
            }
        }
        if (isL2) {
            #pragma unroll
            for (int g = 0; g < 3; ++g) {
                const int col = g * 64 + ut * 16 + lc;
                #pragma unroll
                for (int kk = 0; kk < 2; ++kk) {
                    bf16x8 v;
                    #pragma unroll
                    for (int e = 0; e < 8; ++e)
                        v[e] = (short)f2bf(U2[(8 * lg + 32 * kk + e) * U3 + col]);
                    fb[6 + g * 2 + kk] = v;
                }
            }
        } else {
            #pragma unroll
            for (int q = 6; q < 12; ++q) fb[q] = fb[q - 6];  // keep defined
        }
    }

    // biases as loop-invariant MFMA C-operand quads
    float bias_z, bias_r, bias_h, bias_h2 = 0.0f;
    if (!isL2) {
        bias_z = b1[U3 + cz]; bias_r = b1[U3 + cr]; bias_h = b1[U3 + ch];
    } else {
        bias_z  = b2[cz] + b2[U3 + cz];
        bias_r  = b2[cr] + b2[U3 + cr];
        bias_h  = b2[ch];         // xh init (input-side bias)
        bias_h2 = b2[U3 + ch];    // hph init (recurrent bias)
    }
    const f32x4 bz4 = {bias_z, bias_z, bias_z, bias_z};
    const f32x4 br4 = {bias_r, bias_r, bias_r, bias_r};
    const f32x4 bh4 = {bias_h, bias_h, bias_h, bias_h};
    const f32x4 bp4 = {bias_h2, bias_h2, bias_h2, bias_h2};
    const f32x4 zq  = {0.0f, 0.0f, 0.0f, 0.0f};

    // ---- xp/token prefetch pipeline (L1 waves). Each lane serves its ONE
    // batch row (rb = lg): 3 embW floats + 1 token per step.
    float xp[2][3];
    int   tok[2];
    const int rowbase = (blk * BPB + lg) * TT;   // this lane's token row
    if (!isL2) {
        const int t0 = tokens[rowbase];
        tok[0] = tokens[rowbase + 1];
        tok[1] = tokens[rowbase + 2];
        xp[0][0] = g_embW[t0 * U3 + cz];
        xp[0][1] = g_embW[t0 * U3 + cr];
        xp[0][2] = g_embW[t0 * U3 + ch];
    }

    float h1o = 0.0f;   // h1(s-1) master copy (L1 waves)
    float h2o = 0.0f;   // h2(s-2) master copy (L2 waves)

    __syncthreads();    // LDS zero-init visible

    const int swzA = (lc & 7) << 4;              // A-read row swizzle (row = lc)
    const int myrow = 4 * lg;                    // this lane's MFMA/LDS row
    const int wswz  = ((myrow & 7) << 4);        // write swizzle for that row
    const int wbyte = myrow * 128 + (((ut * 16 + lc) * 2) ^ wswz);

    #pragma unroll 1
    for (int sb = 0; sb < TT + 1; sb += 2) {      // TT+1 = 4996 steps total
        #pragma unroll
        for (int half = 0; half < 2; ++half) {
            const int s = sb + half;              // step
            char* rdb = hls + half * 4096;        // read buffer
            char* wrb = hls + (half ^ 1) * 4096;  // write buffer

            if (!isL2) {
                // ---- issue global prefetch FIRST: xp for step s+1
                // (tok[half] = tokens[s+1]) and token for s+2 ----
                const int tn = tok[half];
                xp[half ^ 1][0] = g_embW[tn * U3 + cz];
                xp[half ^ 1][1] = g_embW[tn * U3 + cr];
                xp[half ^ 1][2] = g_embW[tn * U3 + ch];
                const int s2 = (s + 2 < TT) ? (s + 2) : (TT - 1);
                tok[half ^ 1] = tokens[rowbase + s2];

                // A-fragments (h1 only): rows=batch (lc), k=units.
                bf16x8 a1_0 = *(const bf16x8*)(rdb + lc * 128 + ((16 * lg) ^ swzA));
                bf16x8 a1_1 = *(const bf16x8*)(rdb + lc * 128 + ((16 * lg + 64) ^ swzA));

                if (s < TT) {   // layer 1 computes h1(s)
                    f32x4 az = MFMA16(a1_0, fb[0], bz4, 0, 0, 0);
                    az       = MFMA16(a1_1, fb[1], az,  0, 0, 0);
                    f32x4 ar = MFMA16(a1_0, fb[2], br4, 0, 0, 0);
                    ar       = MFMA16(a1_1, fb[3], ar,  0, 0, 0);
                    f32x4 ah = MFMA16(a1_0, fb[4], bh4, 0, 0, 0);
                    ah       = MFMA16(a1_1, fb[5], ah,  0, 0, 0);
                    const float z  = fast_sigmoid(xp[half][0] + az[0]);
                    const float rg = fast_sigmoid(xp[half][1] + ar[0]);
                    const float hh = fast_tanh(xp[half][2] + rg * ah[0]);
                    h1o = fmaf(z, h1o - hh, hh);      // z*h + (1-z)*hh
                    *(unsigned short*)(wrb + wbyte) = f2bf(h1o);
                }
            } else {
                // A-fragments: h1 (for W2) and h2 (for U2)
                bf16x8 a1_0 = *(const bf16x8*)(rdb + lc * 128 + ((16 * lg) ^ swzA));
                bf16x8 a1_1 = *(const bf16x8*)(rdb + lc * 128 + ((16 * lg + 64) ^ swzA));
                bf16x8 a2_0 = *(const bf16x8*)(rdb + 2048 + lc * 128 + ((16 * lg) ^ swzA));
                bf16x8 a2_1 = *(const bf16x8*)(rdb + 2048 + lc * 128 + ((16 * lg + 64) ^ swzA));

                if (s > 0) {    // layer 2 computes h2(s-1)
                    // z/r: two 2-dep chains + 1 add (was one 4-dep chain)
                    f32x4 az1 = MFMA16(a1_0, fb[0],  bz4, 0, 0, 0);  // h1@W2 (z)
                    az1       = MFMA16(a1_1, fb[1],  az1, 0, 0, 0);
                    f32x4 az2 = MFMA16(a2_0, fb[6],  zq,  0, 0, 0);  // h2@U2 (z)
                    az2       = MFMA16(a2_1, fb[7],  az2, 0, 0, 0);
                    f32x4 ar1 = MFMA16(a1_0, fb[2],  br4, 0, 0, 0);
                    ar1       = MFMA16(a1_1, fb[3],  ar1, 0, 0, 0);
                    f32x4 ar2 = MFMA16(a2_0, fb[8],  zq,  0, 0, 0);
                    ar2       = MFMA16(a2_1, fb[9],  ar2, 0, 0, 0);
                    f32x4 ax  = MFMA16(a1_0, fb[4],  bh4, 0, 0, 0);  // xh
                    ax        = MFMA16(a1_1, fb[5],  ax,  0, 0, 0);
                    f32x4 ap  = MFMA16(a2_0, fb[10], bp4, 0, 0, 0);  // hph
                    ap        = MFMA16(a2_1, fb[11], ap,  0, 0, 0);
                    const float z  = fast_sigmoid(az1[0] + az2[0]);
                    const float rg = fast_sigmoid(ar1[0] + ar2[0]);
                    const float hh = fast_tanh(ax[0] + rg * ap[0]);
                    h2o = fmaf(z, h2o - hh, hh);      // z*h + (1-z)*hh
                    *(unsigned short*)(wrb + 2048 + wbyte) = f2bf(h2o);
                }
            }
            __syncthreads();
        }
    }

    // ---- output head: h2(TT-1) sits in buf0/which=1 (step TT wrote buf0).
    // Lane j (0..3) of wave 0 handles batch row j at LDS row 4*j.
    if (wave == 0 && lane < BPB) {
        const int row = 4 * lane;
        float acc = bout[0];
        #pragma unroll 8
        for (int u = 0; u < UU; ++u) {
            const unsigned short hv = *(const unsigned short*)(hls + 2048 +
                row * 128 + ((u * 2) ^ ((row & 7) << 4)));
            acc = fmaf(bf2f(hv), Wout[u], acc);
        }
        out[blk * BPB + lane] = fast_sigmoid(acc);
    }
}

extern "C" void kernel_launch(void* const* d_in, const int* in_sizes, int n_in,
                              void* d_out, int out_size, void* d_ws, size_t ws_size,
                              hipStream_t stream) {
    const int*   tokens = (const int*)  d_in[0];
    const float* emb    = (const float*)d_in[1];
    const float* W1     = (const float*)d_in[2];
    const float* U1w    = (const float*)d_in[3];
    const float* b1     = (const float*)d_in[4];
    const float* W2     = (const float*)d_in[5];
    const float* U2w    = (const float*)d_in[6];
    const float* b2     = (const float*)d_in[7];
    const float* Wout   = (const float*)d_in[8];
    const float* bout   = (const float*)d_in[9];
    float* out = (float*)d_out;

    gru_embw_kernel<<<VV, 192, 0, stream>>>(emb, W1, b1);
    gru_scan_kernel<<<NBLK, 512, 0, stream>>>(tokens, U1w, b1, W2, U2w,
                                              b2, Wout, bout, out);
}

// Round 7
// 1645.255 us; speedup vs baseline: 1.2107x; 1.0025x over previous
//
#include <hip/hip_runtime.h>

#define BB 64
#define TT 4995
#define VV 4096
#define EE 100
#define UU 64
#define U3 192
#define BPB 4             // batch rows per block (spread across D lane-groups)
#define NBLK (BB / BPB)   // 16 blocks

using bf16x8 = __attribute__((ext_vector_type(8))) short;
using f32x4  = __attribute__((ext_vector_type(4))) float;

#define MFMA16 __builtin_amdgcn_mfma_f32_16x16x32_bf16

// LDS-visibility-only barrier: does NOT drain vmcnt, so each wave's global
// prefetches stay in flight across steps (consumed only by the issuing wave;
// compiler inserts per-use vmcnt waits). sched_barrier(0) fences pin all
// surrounding memory ops (rule: hipcc may otherwise hoist ops past inline-asm
// waitcnt). lgkmcnt(0) makes this wave's ds_writes visible before s_barrier.
#define LDS_BARRIER()                                   \
    do {                                                \
        __builtin_amdgcn_sched_barrier(0);              \
        asm volatile("s_waitcnt lgkmcnt(0)" ::: "memory"); \
        __builtin_amdgcn_s_barrier();                   \
        __builtin_amdgcn_sched_barrier(0);              \
    } while (0)

// Static device workspace: embW[v][k] = (emb @ W1 + b1[0])[v][k], 3.07 MB (L2-resident).
__device__ float g_embW[VV * U3];

__device__ __forceinline__ float fast_sigmoid(float x) {
    return __builtin_amdgcn_rcpf(1.0f + __expf(-x));
}
__device__ __forceinline__ float fast_tanh(float x) {
    return __builtin_amdgcn_rcpf(1.0f + __expf(-2.0f * x)) * 2.0f - 1.0f;
}
// f32 -> bf16 round-to-nearest-even
__device__ __forceinline__ unsigned short f2bf(float f) {
    unsigned u = __float_as_uint(f);
    return (unsigned short)((u + 0x7FFFu + ((u >> 16) & 1u)) >> 16);
}
__device__ __forceinline__ float bf2f(unsigned short h) {
    return __uint_as_float(((unsigned)h) << 16);
}

// Kernel A: embW[v][k] = sum_j emb[v][j] * W1[j][k] + b1[0][k]  (fp32 table)
__global__ void gru_embw_kernel(const float* __restrict__ emb,
                                const float* __restrict__ W1,
                                const float* __restrict__ b1) {
    __shared__ float row[EE];
    const int v = blockIdx.x;
    const int k = threadIdx.x;  // 0..191
    if (k < EE) row[k] = emb[v * EE + k];
    __syncthreads();
    float acc = b1[k];
    #pragma unroll 4
    for (int j = 0; j < EE; ++j)
        acc = fmaf(row[j], W1[j * U3 + k], acc);
    g_embW[v * U3 + k] = acc;
}

// Kernel B: MFMA-based fused 2-layer GRU scan, 16 blocks x 4 batch rows.
// Structure = R6 (verified). R7 delta (ONE mechanism): in-loop barrier no
// longer drains vmcnt (LDS_BARRIER above), and the xp/token prefetch pipeline
// is deepened to 4 phases (xp issued 2 steps ahead ~1400cy slack, tokens 4
// ahead) so even HBM-miss latency (~900cy) stays off the critical path.
__global__ __launch_bounds__(512, 1)
void gru_scan_kernel(const int* __restrict__ tokens,
                     const float* __restrict__ U1,
                     const float* __restrict__ b1,
                     const float* __restrict__ W2,
                     const float* __restrict__ U2,
                     const float* __restrict__ b2,
                     const float* __restrict__ Wout,
                     const float* __restrict__ bout,
                     float* __restrict__ out) {
    const int blk  = blockIdx.x;
    const int tid  = threadIdx.x;
    const int wave = tid >> 6;
    const int lane = tid & 63;
    const int lg   = lane >> 4;   // 0..3: k-chunk group (A/B), row group (D)
    const int lc   = lane & 15;   // 0..15: A-row / D-col
    const bool isL2 = (wave >= 4);
    const int ut   = wave & 3;    // unit tile (16 units) this wave owns

    // h state: [buf(2)][which(2: h1,h2)][row 16][unit 64] bf16, XOR-swizzled:
    // byte = ((buf*2+which)*16 + row)*128 + ((unit*2) ^ ((row&7)<<4))
    // Rows != 0,4,8,12 are never written -> stay zero (harmless in MFMA).
    __shared__ __align__(16) char hls[8192];
    for (int i = tid; i < 2048; i += 512) ((int*)hls)[i] = 0;

    // ---- weight B-fragments (once). k-map: k = 8*lg + 32*kk + e.
    // A uses the same k-map, so any HW k-permutation cancels (A/B mirrored).
    bf16x8 fb[12];
    const int cz = ut * 16 + lc;          // z gate column
    const int cr = 64 + ut * 16 + lc;     // r gate column
    const int ch = 128 + ut * 16 + lc;    // hh gate column
    {
        const float* M0 = isL2 ? W2 : U1;
        #pragma unroll
        for (int g = 0; g < 3; ++g) {
            const int col = g * 64 + ut * 16 + lc;
            #pragma unroll
            for (int kk = 0; kk < 2; ++kk) {
                bf16x8 v;
                #pragma unroll
                for (int e = 0; e < 8; ++e)
                    v[e] = (short)f2bf(M0[(8 * lg + 32 * kk + e) * U3 + col]);
                fb[g * 2 + kk] = v;
            }
        }
        if (isL2) {
            #pragma unroll
            for (int g = 0; g < 3; ++g) {
                const int col = g * 64 + ut * 16 + lc;
                #pragma unroll
                for (int kk = 0; kk < 2; ++kk) {
                    bf16x8 v;
                    #pragma unroll
                    for (int e = 0; e < 8; ++e)
                        v[e] = (short)f2bf(U2[(8 * lg + 32 * kk + e) * U3 + col]);
                    fb[6 + g * 2 + kk] = v;
                }
            }
        } else {
            #pragma unroll
            for (int q = 6; q < 12; ++q) fb[q] = fb[q - 6];  // keep defined
        }
    }

    // biases as loop-invariant MFMA C-operand quads
    float bias_z, bias_r, bias_h, bias_h2 = 0.0f;
    if (!isL2) {
        bias_z = b1[U3 + cz]; bias_r = b1[U3 + cr]; bias_h = b1[U3 + ch];
    } else {
        bias_z  = b2[cz] + b2[U3 + cz];
        bias_r  = b2[cr] + b2[U3 + cr];
        bias_h  = b2[ch];         // xh init (input-side bias)
        bias_h2 = b2[U3 + ch];    // hph init (recurrent bias)
    }
    const f32x4 bz4 = {bias_z, bias_z, bias_z, bias_z};
    const f32x4 br4 = {bias_r, bias_r, bias_r, bias_r};
    const f32x4 bh4 = {bias_h, bias_h, bias_h, bias_h};
    const f32x4 bp4 = {bias_h2, bias_h2, bias_h2, bias_h2};
    const f32x4 zq  = {0.0f, 0.0f, 0.0f, 0.0f};

    // ---- xp/token prefetch pipeline (L1 waves), DEPTH 4 (phase-static).
    // Invariant at top of step s: xp[s&3], xp[(s+1)&3] valid; xp[(s+2)&3]
    // issued here (consumed 2 steps / ~1400cy later); tok[(s+2)&3] holds
    // tokens[s+2]; tokens[s+4] loaded here into tok[s&3] (4-step slack).
    float xp[4][3];
    int   tok[4];
    const int rowbase = (blk * BPB + lg) * TT;   // this lane's token row
    if (!isL2) {
        const int t0 = tokens[rowbase];
        const int t1 = tokens[rowbase + 1];
        tok[2] = tokens[rowbase + 2];
        tok[3] = tokens[rowbase + 3];
        tok[0] = 0; tok[1] = 0;                  // defined; overwritten at s=0,1
        xp[0][0] = g_embW[t0 * U3 + cz];
        xp[0][1] = g_embW[t0 * U3 + cr];
        xp[0][2] = g_embW[t0 * U3 + ch];
        xp[1][0] = g_embW[t1 * U3 + cz];
        xp[1][1] = g_embW[t1 * U3 + cr];
        xp[1][2] = g_embW[t1 * U3 + ch];
        #pragma unroll
        for (int q = 2; q < 4; ++q)
            xp[q][0] = xp[q][1] = xp[q][2] = 0.0f;  // defined; filled at s=0,1
    }

    float h1o = 0.0f;   // h1(s-1) master copy (L1 waves)
    float h2o = 0.0f;   // h2(s-2) master copy (L2 waves)

    __syncthreads();    // full barrier once after LDS zero-init

    const int swzA = (lc & 7) << 4;              // A-read row swizzle (row = lc)
    const int myrow = 4 * lg;                    // this lane's MFMA/LDS row
    const int wswz  = ((myrow & 7) << 4);        // write swizzle for that row
    const int wbyte = myrow * 128 + (((ut * 16 + lc) * 2) ^ wswz);

    #pragma unroll 1
    for (int sq = 0; sq < TT + 1; sq += 4) {      // TT+1 = 4996 = 4*1249 steps
        #pragma unroll
        for (int ph = 0; ph < 4; ++ph) {
            const int s = sq + ph;                // step
            char* rdb = hls + (ph & 1) * 4096;        // read buffer
            char* wrb = hls + ((ph & 1) ^ 1) * 4096;  // write buffer

            if (!isL2) {
                // ---- issue global prefetch FIRST: embW rows for step s+2
                // (token held in tok[(s+2)&3]) and token for step s+4 ----
                const int tn = tok[(ph + 2) & 3];
                xp[(ph + 2) & 3][0] = g_embW[tn * U3 + cz];
                xp[(ph + 2) & 3][1] = g_embW[tn * U3 + cr];
                xp[(ph + 2) & 3][2] = g_embW[tn * U3 + ch];
                const int s4 = (s + 4 < TT) ? (s + 4) : (TT - 1);
                tok[ph & 3] = tokens[rowbase + s4];

                // A-fragments (h1 only): rows=batch (lc), k=units.
                bf16x8 a1_0 = *(const bf16x8*)(rdb + lc * 128 + ((16 * lg) ^ swzA));
                bf16x8 a1_1 = *(const bf16x8*)(rdb + lc * 128 + ((16 * lg + 64) ^ swzA));

                if (s < TT) {   // layer 1 computes h1(s)
                    f32x4 az = MFMA16(a1_0, fb[0], bz4, 0, 0, 0);
                    az       = MFMA16(a1_1, fb[1], az,  0, 0, 0);
                    f32x4 ar = MFMA16(a1_0, fb[2], br4, 0, 0, 0);
                    ar       = MFMA16(a1_1, fb[3], ar,  0, 0, 0);
                    f32x4 ah = MFMA16(a1_0, fb[4], bh4, 0, 0, 0);
                    ah       = MFMA16(a1_1, fb[5], ah,  0, 0, 0);
                    const float z  = fast_sigmoid(xp[ph][0] + az[0]);
                    const float rg = fast_sigmoid(xp[ph][1] + ar[0]);
                    const float hh = fast_tanh(xp[ph][2] + rg * ah[0]);
                    h1o = fmaf(z, h1o - hh, hh);      // z*h + (1-z)*hh
                    *(unsigned short*)(wrb + wbyte) = f2bf(h1o);
                }
            } else {
                // A-fragments: h1 (for W2) and h2 (for U2)
                bf16x8 a1_0 = *(const bf16x8*)(rdb + lc * 128 + ((16 * lg) ^ swzA));
                bf16x8 a1_1 = *(const bf16x8*)(rdb + lc * 128 + ((16 * lg + 64) ^ swzA));
                bf16x8 a2_0 = *(const bf16x8*)(rdb + 2048 + lc * 128 + ((16 * lg) ^ swzA));
                bf16x8 a2_1 = *(const bf16x8*)(rdb + 2048 + lc * 128 + ((16 * lg + 64) ^ swzA));

                if (s > 0) {    // layer 2 computes h2(s-1)
                    // z/r: two 2-dep chains + 1 add
                    f32x4 az1 = MFMA16(a1_0, fb[0],  bz4, 0, 0, 0);  // h1@W2 (z)
                    az1       = MFMA16(a1_1, fb[1],  az1, 0, 0, 0);
                    f32x4 az2 = MFMA16(a2_0, fb[6],  zq,  0, 0, 0);  // h2@U2 (z)
                    az2       = MFMA16(a2_1, fb[7],  az2, 0, 0, 0);
                    f32x4 ar1 = MFMA16(a1_0, fb[2],  br4, 0, 0, 0);
                    ar1       = MFMA16(a1_1, fb[3],  ar1, 0, 0, 0);
                    f32x4 ar2 = MFMA16(a2_0, fb[8],  zq,  0, 0, 0);
                    ar2       = MFMA16(a2_1, fb[9],  ar2, 0, 0, 0);
                    f32x4 ax  = MFMA16(a1_0, fb[4],  bh4, 0, 0, 0);  // xh
                    ax        = MFMA16(a1_1, fb[5],  ax,  0, 0, 0);
                    f32x4 ap  = MFMA16(a2_0, fb[10], bp4, 0, 0, 0);  // hph
                    ap        = MFMA16(a2_1, fb[11], ap,  0, 0, 0);
                    const float z  = fast_sigmoid(az1[0] + az2[0]);
                    const float rg = fast_sigmoid(ar1[0] + ar2[0]);
                    const float hh = fast_tanh(ax[0] + rg * ap[0]);
                    h2o = fmaf(z, h2o - hh, hh);      // z*h + (1-z)*hh
                    *(unsigned short*)(wrb + 2048 + wbyte) = f2bf(h2o);
                }
            }
            LDS_BARRIER();
        }
    }

    // ---- output head: h2(TT-1) sits in buf0/which=1 (step TT wrote buf0).
    // Lane j (0..3) of wave 0 handles batch row j at LDS row 4*j.
    if (wave == 0 && lane < BPB) {
        const int row = 4 * lane;
        float acc = bout[0];
        #pragma unroll 8
        for (int u = 0; u < UU; ++u) {
            const unsigned short hv = *(const unsigned short*)(hls + 2048 +
                row * 128 + ((u * 2) ^ ((row & 7) << 4)));
            acc = fmaf(bf2f(hv), Wout[u], acc);
        }
        out[blk * BPB + lane] = fast_sigmoid(acc);
    }
}

extern "C" void kernel_launch(void* const* d_in, const int* in_sizes, int n_in,
                              void* d_out, int out_size, void* d_ws, size_t ws_size,
                              hipStream_t stream) {
    const int*   tokens = (const int*)  d_in[0];
    const float* emb    = (const float*)d_in[1];
    const float* W1     = (const float*)d_in[2];
    const float* U1w    = (const float*)d_in[3];
    const float* b1     = (const float*)d_in[4];
    const float* W2     = (const float*)d_in[5];
    const float* U2w    = (const float*)d_in[6];
    const float* b2     = (const float*)d_in[7];
    const float* Wout   = (const float*)d_in[8];
    const float* bout   = (const float*)d_in[9];
    float* out = (float*)d_out;

    gru_embw_kernel<<<VV, 192, 0, stream>>>(emb, W1, b1);
    gru_scan_kernel<<<NBLK, 512, 0, stream>>>(tokens, U1w, b1, W2, U2w,
                                              b2, Wout, bout, out);
}